// Round 4
// baseline (430.342 us; speedup 1.0000x reference)
//
#include <hip/hip_runtime.h>
#include <hip/hip_bf16.h>
#include <math.h>

// Problem constants (fixed by setup_inputs)
#define S_   64
#define H_   32
#define D_   128
#define KVH_ 8
#define G_   4
#define BS_  16
#define MB_  128
#define LMAX_ 2048
#define PART_ 256

#define SCALE_ 0.08838834764831845f  // 1/sqrt(128)
#define MINIT_ -1.0e30f              // finite "neg-inf" so corr=exp(m-mn) never NaN

// Partial kernel: one WG per (seq, kv_head, partition of 256 tokens).
// 256 threads = 8 groups of 32 lanes; group owns 2 consecutive 16-token pages
// (32 tokens) processed as 8 branch-free batches of 4 with 2-deep register
// double-buffering. ALL loads are unconditional (any block-table entry is a
// valid page) so the compiler can emit counted vmcnt waits; only scores are
// masked. Lane owns a 4-float slice of D.
__global__ __launch_bounds__(256)
void pa_partial(const float* __restrict__ q,
                const float* __restrict__ kc,
                const float* __restrict__ vc,
                const int* __restrict__ bt,
                const int* __restrict__ cl,
                float* __restrict__ ws)
{
    const int s    = blockIdx.z;
    const int kvh  = blockIdx.y;
    const int part = blockIdx.x;

    const int len = cl[s];
    const int t0  = part * PART_;
    if (t0 >= len) return;

    const int tid  = threadIdx.x;
    const int gid  = tid >> 5;   // 0..7
    const int lane = tid & 31;   // 0..31

    const int t_base = t0 + gid * 32;      // group's first token
    const int nv     = len - t_base;       // tokens valid for this group (may be <=0)

    // Q fragments: 4 heads, each lane holds float4 at d = lane*4
    float4 qv[G_];
#pragma unroll
    for (int g = 0; g < G_; ++g)
        qv[g] = *(const float4*)(q + ((size_t)(s * H_ + kvh * G_ + g)) * D_ + lane * 4);

    float  m[G_], l[G_];
    float4 acc[G_];
#pragma unroll
    for (int g = 0; g < G_; ++g) {
        m[g] = MINIT_; l[g] = 0.f;
        acc[g] = make_float4(0.f, 0.f, 0.f, 0.f);
    }

    const int* btr = bt + s * MB_;
    const size_t kvh_off = (size_t)kvh * (BS_ * D_);

    // Two pages cover the group's 32 tokens; page0 <= 126 always.
    const int page0 = t_base >> 4;
    const int bid0  = btr[page0];
    const int bid1  = btr[page0 + 1];
    const float* kp0 = kc + (size_t)bid0 * (KVH_ * BS_ * D_) + kvh_off + lane * 4;
    const float* vp0 = vc + (size_t)bid0 * (KVH_ * BS_ * D_) + kvh_off + lane * 4;
    const float* kp1 = kc + (size_t)bid1 * (KVH_ * BS_ * D_) + kvh_off + lane * 4;
    const float* vp1 = vc + (size_t)bid1 * (KVH_ * BS_ * D_) + kvh_off + lane * 4;

    float4 kb[2][4], vb[2][4];
    // Prologue: batch 0 (page 0, rows 0..3). K first, then V.
#pragma unroll
    for (int r = 0; r < 4; ++r) kb[0][r] = *(const float4*)(kp0 + (size_t)r * D_);
#pragma unroll
    for (int r = 0; r < 4; ++r) vb[0][r] = *(const float4*)(vp0 + (size_t)r * D_);

#pragma unroll
    for (int i = 0; i < 8; ++i) {
        const int cur = i & 1, nxt = cur ^ 1;

        // Unconditional prefetch of batch i+1 (static addressing).
        if (i < 7) {
            const float* kpp = ((i + 1) < 4 ? kp0 : kp1) + (size_t)(((i + 1) & 3) * 4) * D_;
            const float* vpp = ((i + 1) < 4 ? vp0 : vp1) + (size_t)(((i + 1) & 3) * 4) * D_;
#pragma unroll
            for (int r = 0; r < 4; ++r) kb[nxt][r] = *(const float4*)(kpp + (size_t)r * D_);
#pragma unroll
            for (int r = 0; r < 4; ++r) vb[nxt][r] = *(const float4*)(vpp + (size_t)r * D_);
        }

        // Partial dots: 16 independent values.
        float sc[4][G_];
#pragma unroll
        for (int i2 = 0; i2 < 4; ++i2)
#pragma unroll
            for (int g = 0; g < G_; ++g)
                sc[i2][g] = qv[g].x * kb[cur][i2].x + qv[g].y * kb[cur][i2].y +
                            qv[g].z * kb[cur][i2].z + qv[g].w * kb[cur][i2].w;

        // Butterfly reduce across 32 lanes; 16 chains pipeline.
#pragma unroll
        for (int off = 16; off; off >>= 1)
#pragma unroll
            for (int i2 = 0; i2 < 4; ++i2)
#pragma unroll
                for (int g = 0; g < G_; ++g)
                    sc[i2][g] += __shfl_xor(sc[i2][g], off, 32);

        // Scale + mask tokens beyond nv (masked -> -inf; p becomes 0).
#pragma unroll
        for (int i2 = 0; i2 < 4; ++i2) {
            const bool valid = (i * 4 + i2) < nv;
#pragma unroll
            for (int g = 0; g < G_; ++g)
                sc[i2][g] = valid ? sc[i2][g] * SCALE_ : -INFINITY;
        }

        // Batched online-softmax update. m stays finite (>= MINIT_) so
        // corr = exp(m - mn) is never NaN; all-masked batches are no-ops.
#pragma unroll
        for (int g = 0; g < G_; ++g) {
            const float smax = fmaxf(fmaxf(sc[0][g], sc[1][g]),
                                     fmaxf(sc[2][g], sc[3][g]));
            const float mn   = fmaxf(m[g], smax);
            const float corr = __expf(m[g] - mn);
            const float p0 = __expf(sc[0][g] - mn);
            const float p1 = __expf(sc[1][g] - mn);
            const float p2 = __expf(sc[2][g] - mn);
            const float p3 = __expf(sc[3][g] - mn);
            l[g] = l[g] * corr + ((p0 + p1) + (p2 + p3));
            acc[g].x = acc[g].x * corr + p0 * vb[cur][0].x + p1 * vb[cur][1].x + p2 * vb[cur][2].x + p3 * vb[cur][3].x;
            acc[g].y = acc[g].y * corr + p0 * vb[cur][0].y + p1 * vb[cur][1].y + p2 * vb[cur][2].y + p3 * vb[cur][3].y;
            acc[g].z = acc[g].z * corr + p0 * vb[cur][0].z + p1 * vb[cur][1].z + p2 * vb[cur][2].z + p3 * vb[cur][3].z;
            acc[g].w = acc[g].w * corr + p0 * vb[cur][0].w + p1 * vb[cur][1].w + p2 * vb[cur][2].w + p3 * vb[cur][3].w;
            m[g] = mn;
        }
    }

    // Combine the 8 groups inside the WG via LDS.
    __shared__ float lm[8][G_];
    __shared__ float ll[8][G_];
    __shared__ float lacc[8][G_][D_];   // 16 KB

#pragma unroll
    for (int g = 0; g < G_; ++g) {
        if (lane == 0) { lm[gid][g] = m[g]; ll[gid][g] = l[g]; }
        *(float4*)&lacc[gid][g][lane * 4] = acc[g];
    }
    __syncthreads();

    // 512 (g,d) elements over 256 threads: 2 each.
    // Group 0 is always non-empty (t0 < len), so M is a real max; empty
    // groups carry (m=MINIT_, l=0, acc=0) -> weight exp(MINIT_-M)*0 = 0.
    float* pbase = ws + (((size_t)(s * KVH_ + kvh) * (LMAX_ / PART_) + part) * G_) * 130;
#pragma unroll
    for (int i = 0; i < 2; ++i) {
        const int idx = tid + 256 * i;
        const int g = idx >> 7;
        const int d = idx & 127;
        float M = lm[0][g];
#pragma unroll
        for (int r = 1; r < 8; ++r) M = fmaxf(M, lm[r][g]);
        float L = 0.f, val = 0.f;
#pragma unroll
        for (int r = 0; r < 8; ++r) {
            const float w = __expf(lm[r][g] - M);
            L   += w * ll[r][g];
            val += w * lacc[r][g][d];
        }
        float* pb = pbase + (size_t)g * 130;
        if (d == 0) { pb[0] = M; pb[1] = L; }
        pb[2 + d] = val;
    }
}

// Combine kernel: one WG (128 threads) per (seq, head); reduce over partitions.
__global__ __launch_bounds__(128)
void pa_combine(const float* __restrict__ ws,
                const int* __restrict__ cl,
                float* __restrict__ out)
{
    const int h = blockIdx.x;   // 0..31
    const int s = blockIdx.y;   // 0..63
    const int kvh = h >> 2;
    const int g   = h & 3;
    const int d   = threadIdx.x;
    const int maxP = LMAX_ / PART_;

    const int len = cl[s];
    const int np  = (len + PART_ - 1) / PART_;

    const float* base = ws + ((size_t)(s * KVH_ + kvh) * maxP) * (G_ * 130) + (size_t)g * 130;

    float M = MINIT_;
    for (int p = 0; p < np; ++p) M = fmaxf(M, base[(size_t)p * (G_ * 130)]);

    float L = 0.f, val = 0.f;
    for (int p = 0; p < np; ++p) {
        const float* pb = base + (size_t)p * (G_ * 130);
        const float w = __expf(pb[0] - M);
        L   += w * pb[1];
        val += w * pb[2 + d];
    }
    out[((size_t)s * H_ + h) * D_ + d] = val / L;
}

extern "C" void kernel_launch(void* const* d_in, const int* in_sizes, int n_in,
                              void* d_out, int out_size, void* d_ws, size_t ws_size,
                              hipStream_t stream)
{
    const float* q  = (const float*)d_in[0];
    const float* kc = (const float*)d_in[1];
    const float* vc = (const float*)d_in[2];
    const int*   bt = (const int*)d_in[3];
    const int*   cl = (const int*)d_in[4];
    float* out = (float*)d_out;
    float* ws  = (float*)d_ws;

    // ws need: 64*8*8*4*130*4 B = 8.5 MB (harness guarantees ws_size >= this
    // in practice; layout indexed with maxP = LMAX_/PART_ = 8).
    dim3 grid1(LMAX_ / PART_, KVH_, S_);
    pa_partial<<<grid1, 256, 0, stream>>>(q, kc, vc, bt, cl, ws);

    dim3 grid2(H_, S_);
    pa_combine<<<grid2, 128, 0, stream>>>(ws, cl, out);
}

// Round 5
// 244.116 us; speedup vs baseline: 1.7629x; 1.7629x over previous
//
#include <hip/hip_runtime.h>
#include <hip/hip_bf16.h>
#include <math.h>

// Problem constants (fixed by setup_inputs)
#define S_   64
#define H_   32
#define D_   128
#define KVH_ 8
#define G_   4
#define BS_  16
#define MB_  128
#define LMAX_ 2048
#define PART_ 256
#define MAXP_ (LMAX_ / PART_)   // 8

#define SCALE_ 0.08838834764831845f  // 1/sqrt(128)
#define MINIT_ -1.0e30f              // finite "neg-inf": corr=exp(m-mn) never NaN

typedef __attribute__((address_space(1))) const float gfloat;
typedef __attribute__((address_space(3))) float lfloat;

// One 64-lane wave per WG, one (seq, kv_head, 256-token partition) per WG.
// Per page (16 tokens): DMA K+V page (16 KB) into wave-private LDS with
// global_load_lds (no VGPR cost), wait, compute. Latency hidden by ~10
// independent WGs/CU (LDS-limited), not by per-wave pipelining.
// Lane layout: half = lane/32 handles tokens half*8..half*8+7 of the page,
// lane%32 owns a float4 slice of D.
__global__ __launch_bounds__(64)
void pa_partial(const float* __restrict__ q,
                const float* __restrict__ kc,
                const float* __restrict__ vc,
                const int* __restrict__ bt,
                const int* __restrict__ cl,
                float* __restrict__ ws)
{
    const int s    = blockIdx.z;
    const int kvh  = blockIdx.y;
    const int part = blockIdx.x;

    const int len = cl[s];
    const int t0  = part * PART_;
    if (t0 >= len) return;
    const int npages = min(PART_ / BS_, ((len - t0) + BS_ - 1) >> 4);

    const int lane = threadIdx.x;   // 0..63
    const int half = lane >> 5;     // 0..1
    const int l32  = lane & 31;     // 0..31

    __shared__ float sK[BS_ * D_];  // 8 KB
    __shared__ float sV[BS_ * D_];  // 8 KB

    // Q fragments: 4 heads, float4 at d = l32*4 (same in both halves)
    float4 qv[G_];
#pragma unroll
    for (int g = 0; g < G_; ++g)
        qv[g] = *(const float4*)(q + ((size_t)(s * H_ + kvh * G_ + g)) * D_ + l32 * 4);

    float  m[G_], l[G_];
    float4 acc[G_];
#pragma unroll
    for (int g = 0; g < G_; ++g) {
        m[g] = MINIT_; l[g] = 0.f;
        acc[g] = make_float4(0.f, 0.f, 0.f, 0.f);
    }

    const int* btr = bt + s * MB_;
    const size_t kvh_off = (size_t)kvh * (BS_ * D_);

    for (int p = 0; p < npages; ++p) {
        const int bid = btr[(t0 >> 4) + p];
        const float* kpage = kc + (size_t)bid * (KVH_ * BS_ * D_) + kvh_off;
        const float* vpage = vc + (size_t)bid * (KVH_ * BS_ * D_) + kvh_off;

        // DMA the 16-token page: 8x 1KB chunks each for K and V.
        // LDS dest is wave-uniform base (+ lane*16 in HW); global src per-lane.
#pragma unroll
        for (int j = 0; j < 8; ++j)
            __builtin_amdgcn_global_load_lds((gfloat*)(kpage + j * 256 + lane * 4),
                                             (lfloat*)&sK[j * 256], 16, 0, 0);
#pragma unroll
        for (int j = 0; j < 8; ++j)
            __builtin_amdgcn_global_load_lds((gfloat*)(vpage + j * 256 + lane * 4),
                                             (lfloat*)&sV[j * 256], 16, 0, 0);
        asm volatile("s_waitcnt vmcnt(0)" ::: "memory");
        __builtin_amdgcn_sched_barrier(0);

        const int tpage = t0 + p * BS_ + half * 8;  // this half's first token

        // 2 batches of 4 tokens per half.
#pragma unroll
        for (int b = 0; b < 2; ++b) {
            float4 k4[4], v4[4];
#pragma unroll
            for (int i = 0; i < 4; ++i) {
                const int row = half * 8 + b * 4 + i;
                k4[i] = *(const float4*)&sK[row * D_ + l32 * 4];
                v4[i] = *(const float4*)&sV[row * D_ + l32 * 4];
            }

            float sc[4][G_];
#pragma unroll
            for (int i = 0; i < 4; ++i)
#pragma unroll
                for (int g = 0; g < G_; ++g)
                    sc[i][g] = qv[g].x * k4[i].x + qv[g].y * k4[i].y +
                               qv[g].z * k4[i].z + qv[g].w * k4[i].w;

            // Butterfly reduce within each 32-lane half; 16 chains pipeline.
#pragma unroll
            for (int off = 16; off; off >>= 1)
#pragma unroll
                for (int i = 0; i < 4; ++i)
#pragma unroll
                    for (int g = 0; g < G_; ++g)
                        sc[i][g] += __shfl_xor(sc[i][g], off, 32);

            // Scale + mask tokens beyond len.
#pragma unroll
            for (int i = 0; i < 4; ++i) {
                const bool valid = (tpage + b * 4 + i) < len;
#pragma unroll
                for (int g = 0; g < G_; ++g)
                    sc[i][g] = valid ? sc[i][g] * SCALE_ : -INFINITY;
            }

            // Online-softmax update (m finite always; masked p -> 0).
#pragma unroll
            for (int g = 0; g < G_; ++g) {
                const float smax = fmaxf(fmaxf(sc[0][g], sc[1][g]),
                                         fmaxf(sc[2][g], sc[3][g]));
                const float mn   = fmaxf(m[g], smax);
                const float corr = __expf(m[g] - mn);
                const float p0 = __expf(sc[0][g] - mn);
                const float p1 = __expf(sc[1][g] - mn);
                const float p2 = __expf(sc[2][g] - mn);
                const float p3 = __expf(sc[3][g] - mn);
                l[g] = l[g] * corr + ((p0 + p1) + (p2 + p3));
                acc[g].x = acc[g].x * corr + p0 * v4[0].x + p1 * v4[1].x + p2 * v4[2].x + p3 * v4[3].x;
                acc[g].y = acc[g].y * corr + p0 * v4[0].y + p1 * v4[1].y + p2 * v4[2].y + p3 * v4[3].y;
                acc[g].z = acc[g].z * corr + p0 * v4[0].z + p1 * v4[1].z + p2 * v4[2].z + p3 * v4[3].z;
                acc[g].w = acc[g].w * corr + p0 * v4[0].w + p1 * v4[1].w + p2 * v4[2].w + p3 * v4[3].w;
                m[g] = mn;
            }
        }
    }

    // Merge the two halves with width-64 shuffles (partner = lane ^ 32).
    float* pbase = ws + (((size_t)(s * KVH_ + kvh) * MAXP_ + part) * G_) * 130;
#pragma unroll
    for (int g = 0; g < G_; ++g) {
        const float mo = __shfl_xor(m[g], 32, 64);
        const float lo = __shfl_xor(l[g], 32, 64);
        const float ox = __shfl_xor(acc[g].x, 32, 64);
        const float oy = __shfl_xor(acc[g].y, 32, 64);
        const float oz = __shfl_xor(acc[g].z, 32, 64);
        const float ow = __shfl_xor(acc[g].w, 32, 64);
        const float M  = fmaxf(m[g], mo);
        const float w  = __expf(m[g] - M);
        const float wo = __expf(mo - M);
        const float L  = w * l[g] + wo * lo;
        float4 A;
        A.x = w * acc[g].x + wo * ox;
        A.y = w * acc[g].y + wo * oy;
        A.z = w * acc[g].z + wo * oz;
        A.w = w * acc[g].w + wo * ow;
        if (half == 0) {
            float* pb = pbase + (size_t)g * 130;
            if (l32 == 0) { pb[0] = M; pb[1] = L; }
            *(float4*)(pb + 2 + l32 * 4) = A;
        }
    }
}

// Combine kernel: one WG (128 threads) per (seq, head); reduce over partitions.
__global__ __launch_bounds__(128)
void pa_combine(const float* __restrict__ ws,
                const int* __restrict__ cl,
                float* __restrict__ out)
{
    const int h = blockIdx.x;   // 0..31
    const int s = blockIdx.y;   // 0..63
    const int kvh = h >> 2;
    const int g   = h & 3;
    const int d   = threadIdx.x;

    const int len = cl[s];
    const int np  = (len + PART_ - 1) / PART_;

    const float* base = ws + ((size_t)(s * KVH_ + kvh) * MAXP_) * (G_ * 130) + (size_t)g * 130;

    float M = MINIT_;
    for (int p = 0; p < np; ++p) M = fmaxf(M, base[(size_t)p * (G_ * 130)]);

    float L = 0.f, val = 0.f;
    for (int p = 0; p < np; ++p) {
        const float* pb = base + (size_t)p * (G_ * 130);
        const float w = __expf(pb[0] - M);
        L   += w * pb[1];
        val += w * pb[2 + d];
    }
    out[((size_t)s * H_ + h) * D_ + d] = val / L;
}

extern "C" void kernel_launch(void* const* d_in, const int* in_sizes, int n_in,
                              void* d_out, int out_size, void* d_ws, size_t ws_size,
                              hipStream_t stream)
{
    const float* q  = (const float*)d_in[0];
    const float* kc = (const float*)d_in[1];
    const float* vc = (const float*)d_in[2];
    const int*   bt = (const int*)d_in[3];
    const int*   cl = (const int*)d_in[4];
    float* out = (float*)d_out;
    float* ws  = (float*)d_ws;

    // ws layout: [S_][KVH_][MAXP_][G_][130] floats = 8.5 MB.
    dim3 grid1(MAXP_, KVH_, S_);
    pa_partial<<<grid1, 64, 0, stream>>>(q, kc, vc, bt, cl, ws);

    dim3 grid2(H_, S_);
    pa_combine<<<grid2, 128, 0, stream>>>(ws, cl, out);
}

// Round 6
// 197.724 us; speedup vs baseline: 2.1765x; 1.2346x over previous
//
#include <hip/hip_runtime.h>
#include <hip/hip_bf16.h>
#include <math.h>

// Problem constants (fixed by setup_inputs)
#define S_   64
#define H_   32
#define D_   128
#define KVH_ 8
#define G_   4
#define BS_  16
#define MB_  128
#define LMAX_ 2048

#define SCALE_ 0.08838834764831845f  // 1/sqrt(128)
#define MINIT_ -1.0e30f              // finite "neg-inf": corr=exp(m-mn) never NaN

typedef __attribute__((address_space(1))) const float gfloat;
typedef __attribute__((address_space(3))) float lfloat;

// WG = 256 threads = 4 waves, one (seq, kv_head, PART-token partition).
// Wave w computes query head w (GQA G=4) — all 4 waves consume the SAME
// K/V page staged in LDS, double-buffered, with counted vmcnt + raw
// barriers so the prefetch DMA stays in flight across the barrier.
// Page layout in LDS buffer: K = buf[0..2048), V = buf[2048..4096).
template<int PART>
__global__ __launch_bounds__(256)
void pa_partial(const float* __restrict__ q,
                const float* __restrict__ kc,
                const float* __restrict__ vc,
                const int* __restrict__ bt,
                const int* __restrict__ cl,
                float* __restrict__ ws)
{
    constexpr int MAXP = LMAX_ / PART;
    const int s    = blockIdx.z;
    const int kvh  = blockIdx.y;
    const int part = blockIdx.x;

    const int len = cl[s];
    const int t0  = part * PART;
    if (t0 >= len) return;                       // whole WG exits together
    const int np = min(PART / BS_, ((len - t0) + BS_ - 1) >> 4);

    const int tid  = threadIdx.x;
    const int wid  = tid >> 6;    // 0..3 = query head within group
    const int lane = tid & 63;
    const int half = lane >> 5;   // 0..1: tokens 0-7 / 8-15 of page
    const int l32  = lane & 31;   // float4 slice of D

    __shared__ float sA[2 * BS_ * D_];   // 16 KB: K then V
    __shared__ float sB[2 * BS_ * D_];   // 16 KB

    // This wave's Q fragment (head = wid)
    const float4 qv = *(const float4*)(q + ((size_t)(s * H_ + kvh * G_ + wid)) * D_ + l32 * 4);

    float m = MINIT_, l = 0.f;
    float4 acc = make_float4(0.f, 0.f, 0.f, 0.f);

    const int* btr = bt + s * MB_;
    const size_t kvh_off = (size_t)kvh * (BS_ * D_);

    // Stage page p into buf: per wave 2 K-chunks + 2 V-chunks of 1 KB.
    auto stage = [&](float* buf, int p) {
        const int bid = btr[(t0 >> 4) + p];
        const float* kpage = kc + (size_t)bid * (KVH_ * BS_ * D_) + kvh_off;
        const float* vpage = vc + (size_t)bid * (KVH_ * BS_ * D_) + kvh_off;
#pragma unroll
        for (int r = 0; r < 2; ++r) {
            const int j = 2 * wid + r;           // chunk 0..7
            __builtin_amdgcn_global_load_lds((gfloat*)(kpage + j * 256 + lane * 4),
                                             (lfloat*)&buf[j * 256], 16, 0, 0);
            __builtin_amdgcn_global_load_lds((gfloat*)(vpage + j * 256 + lane * 4),
                                             (lfloat*)&buf[2048 + j * 256], 16, 0, 0);
        }
    };

    // Compute page p from buf (this wave: head wid, all 16 tokens).
    auto compute = [&](const float* buf, int p) {
        const int tbase = t0 + p * BS_ + half * 8;   // half's first token
#pragma unroll
        for (int b = 0; b < 2; ++b) {
            float4 k4[4], v4[4];
#pragma unroll
            for (int i = 0; i < 4; ++i) {
                const int row = half * 8 + b * 4 + i;
                k4[i] = *(const float4*)&buf[row * D_ + l32 * 4];
                v4[i] = *(const float4*)&buf[2048 + row * D_ + l32 * 4];
            }
            float sc[4];
#pragma unroll
            for (int i = 0; i < 4; ++i)
                sc[i] = qv.x * k4[i].x + qv.y * k4[i].y + qv.z * k4[i].z + qv.w * k4[i].w;
#pragma unroll
            for (int off = 16; off; off >>= 1)
#pragma unroll
                for (int i = 0; i < 4; ++i)
                    sc[i] += __shfl_xor(sc[i], off, 32);
#pragma unroll
            for (int i = 0; i < 4; ++i) {
                const bool valid = (tbase + b * 4 + i) < len;
                sc[i] = valid ? sc[i] * SCALE_ : -INFINITY;
            }
            const float smax = fmaxf(fmaxf(sc[0], sc[1]), fmaxf(sc[2], sc[3]));
            const float mn   = fmaxf(m, smax);
            const float corr = __expf(m - mn);
            const float p0 = __expf(sc[0] - mn);
            const float p1 = __expf(sc[1] - mn);
            const float p2 = __expf(sc[2] - mn);
            const float p3 = __expf(sc[3] - mn);
            l = l * corr + ((p0 + p1) + (p2 + p3));
            acc.x = acc.x * corr + p0 * v4[0].x + p1 * v4[1].x + p2 * v4[2].x + p3 * v4[3].x;
            acc.y = acc.y * corr + p0 * v4[0].y + p1 * v4[1].y + p2 * v4[2].y + p3 * v4[3].y;
            acc.z = acc.z * corr + p0 * v4[0].z + p1 * v4[1].z + p2 * v4[2].z + p3 * v4[3].z;
            acc.w = acc.w * corr + p0 * v4[0].w + p1 * v4[1].w + p2 * v4[2].w + p3 * v4[3].w;
            m = mn;
        }
    };

    // Software pipeline: counted vmcnt (never 0 mid-loop) + raw barriers.
    stage(sA, 0);
    int p = 0;
    while (true) {
        // ---- consume A ----
        if (p + 1 < np) {
            stage(sB, p + 1);
            asm volatile("s_waitcnt vmcnt(4)" ::: "memory");
        } else {
            asm volatile("s_waitcnt vmcnt(0)" ::: "memory");
        }
        __builtin_amdgcn_s_barrier();
        __builtin_amdgcn_sched_barrier(0);
        compute(sA, p);
        __builtin_amdgcn_s_barrier();
        if (++p >= np) break;
        // ---- consume B ----
        if (p + 1 < np) {
            stage(sA, p + 1);
            asm volatile("s_waitcnt vmcnt(4)" ::: "memory");
        } else {
            asm volatile("s_waitcnt vmcnt(0)" ::: "memory");
        }
        __builtin_amdgcn_s_barrier();
        __builtin_amdgcn_sched_barrier(0);
        compute(sB, p);
        __builtin_amdgcn_s_barrier();
        if (++p >= np) break;
    }

    // Merge the two halves (partner = lane ^ 32) and write this wave's partial.
    const float mo = __shfl_xor(m, 32, 64);
    const float lo = __shfl_xor(l, 32, 64);
    const float ox = __shfl_xor(acc.x, 32, 64);
    const float oy = __shfl_xor(acc.y, 32, 64);
    const float oz = __shfl_xor(acc.z, 32, 64);
    const float ow = __shfl_xor(acc.w, 32, 64);
    const float M  = fmaxf(m, mo);
    const float w  = __expf(m - M);
    const float wo = __expf(mo - M);
    const float L  = w * l + wo * lo;
    float4 A;
    A.x = w * acc.x + wo * ox;
    A.y = w * acc.y + wo * oy;
    A.z = w * acc.z + wo * oz;
    A.w = w * acc.w + wo * ow;

    float* pb = ws + (((size_t)(s * KVH_ + kvh) * MAXP + part) * G_ + wid) * 130;
    if (half == 0) {
        if (l32 == 0) { pb[0] = M; pb[1] = L; }
        *(float4*)(pb + 2 + l32 * 4) = A;
    }
}

// Combine kernel: one WG (128 threads) per (seq, head); reduce over partitions.
__global__ __launch_bounds__(128)
void pa_combine(const float* __restrict__ ws,
                const int* __restrict__ cl,
                float* __restrict__ out,
                int PART, int maxP)
{
    const int h = blockIdx.x;   // 0..31
    const int s = blockIdx.y;   // 0..63
    const int kvh = h >> 2;
    const int g   = h & 3;
    const int d   = threadIdx.x;

    const int len = cl[s];
    const int np  = (len + PART - 1) / PART;

    const float* base = ws + (((size_t)(s * KVH_ + kvh) * maxP) * G_ + g) * 130;

    float M = MINIT_;
    for (int p = 0; p < np; ++p) M = fmaxf(M, base[(size_t)p * (G_ * 130)]);

    float L = 0.f, val = 0.f;
    for (int p = 0; p < np; ++p) {
        const float* pb = base + (size_t)p * (G_ * 130);
        const float w = __expf(pb[0] - M);
        L   += w * pb[1];
        val += w * pb[2 + d];
    }
    out[((size_t)s * H_ + h) * D_ + d] = val / L;
}

extern "C" void kernel_launch(void* const* d_in, const int* in_sizes, int n_in,
                              void* d_out, int out_size, void* d_ws, size_t ws_size,
                              hipStream_t stream)
{
    const float* q  = (const float*)d_in[0];
    const float* kc = (const float*)d_in[1];
    const float* vc = (const float*)d_in[2];
    const int*   bt = (const int*)d_in[3];
    const int*   cl = (const int*)d_in[4];
    float* out = (float*)d_out;
    float* ws  = (float*)d_ws;

    // ws need: S*KVH*(LMAX/PART)*G*130*4 B. PART=64 -> 34 MB, 128 -> 17 MB,
    // 256 -> 8.5 MB. Pick smallest PART (best load balance) that fits.
    auto need = [](int PARTv) {
        return (size_t)S_ * KVH_ * (LMAX_ / PARTv) * G_ * 130 * sizeof(float);
    };

    if (need(64) <= ws_size) {
        dim3 grid1(LMAX_ / 64, KVH_, S_);
        pa_partial<64><<<grid1, 256, 0, stream>>>(q, kc, vc, bt, cl, ws);
        dim3 grid2(H_, S_);
        pa_combine<<<grid2, 128, 0, stream>>>(ws, cl, out, 64, LMAX_ / 64);
    } else if (need(128) <= ws_size) {
        dim3 grid1(LMAX_ / 128, KVH_, S_);
        pa_partial<128><<<grid1, 256, 0, stream>>>(q, kc, vc, bt, cl, ws);
        dim3 grid2(H_, S_);
        pa_combine<<<grid2, 128, 0, stream>>>(ws, cl, out, 128, LMAX_ / 128);
    } else {
        dim3 grid1(LMAX_ / 256, KVH_, S_);
        pa_partial<256><<<grid1, 256, 0, stream>>>(q, kc, vc, bt, cl, ws);
        dim3 grid2(H_, S_);
        pa_combine<<<grid2, 128, 0, stream>>>(ws, cl, out, 256, LMAX_ / 256);
    }
}